// Round 4
// baseline (129.012 us; speedup 1.0000x reference)
//
#include <hip/hip_runtime.h>
#include <hip/hip_bf16.h>

// out[b,i,j] = sum_h a[h] * tanh(ca[b,i,h] + da[b,j,h] + bias[h])
//   tanh(x) = 1 - 2/(e^{2x}+1);  e^{2x} = pu*pv (pu,pv precomputed via exp2)
// Mixed-pipe inner loop (balance VALU vs transcendental):
//   pairs 0..10  (h 0..21): common-denominator  -> 6 VALU + 1 v_rcp per 2h
//   pairs 11..15 (h 22..31): direct reciprocal  -> 4 VALU + 2 v_rcp per 2h
// pu rows double-buffered in registers (prefetch ii+1 while computing ii).
// Output FLOAT32 (reference dtype).

#define BB    8
#define NC    1024
#define ND    1024
#define DD    64
#define HH    32
#define CHUNK 8
#define NPAIR (HH / 2)
#define SPLIT 11
#define C2    2.885390081777927f   // 2*log2(e)

__global__ __launch_bounds__(256) void proj_cell_kernel(
    const float* __restrict__ cell, const float* __restrict__ w_k,
    const float* __restrict__ bias, float* __restrict__ pu)
{
    int tid = threadIdx.x;
    int h = tid & 31;
    int i = blockIdx.x * 8 + (tid >> 5);
    int b = blockIdx.y;
    const float* crow = cell + ((size_t)(b * NC + i)) * DD;
    float s = bias[h];
    #pragma unroll
    for (int d = 0; d < DD; ++d)
        s = fmaf(crow[d], w_k[d * HH + h], s);
    pu[((size_t)(b * NC + i)) * HH + h] = exp2f(C2 * s);
}

// pv layout: [B][H][ND] so the main kernel's pv loads are j-coalesced.
__global__ __launch_bounds__(256) void proj_drug_kernel(
    const float* __restrict__ drug, const float* __restrict__ w_q,
    float* __restrict__ pv)
{
    __shared__ float sd[64][65];   // +1 pad breaks the 32-bank alias
    int tid = threadIdx.x;
    int b = blockIdx.y;
    int j0 = blockIdx.x * 64;
    const float* dbase = drug + ((size_t)(b * ND + j0)) * DD;
    #pragma unroll
    for (int k = 0; k < 16; ++k) {
        int idx = k * 256 + tid;           // coalesced global read
        sd[idx >> 6][idx & 63] = dbase[idx];
    }
    __syncthreads();
    int jl = tid & 63;       // lane = j  -> coalesced pv writes
    int hg = tid >> 6;       // 0..3, wave-uniform h
    #pragma unroll
    for (int hh = 0; hh < 8; ++hh) {
        int h = hg * 8 + hh;
        float s = 0.f;
        #pragma unroll
        for (int d = 0; d < DD; ++d)
            s = fmaf(sd[jl][d], w_q[d * HH + h], s);
        pv[((size_t)(b * HH + h)) * ND + j0 + jl] = exp2f(C2 * s);
    }
}

__device__ __forceinline__ void load_pu_row(float* dst, const float* __restrict__ src)
{
    #pragma unroll
    for (int h4 = 0; h4 < HH / 4; ++h4) {
        float4 v = reinterpret_cast<const float4*>(src)[h4];  // uniform addr -> s_load
        dst[4 * h4 + 0] = v.x;
        dst[4 * h4 + 1] = v.y;
        dst[4 * h4 + 2] = v.z;
        dst[4 * h4 + 3] = v.w;
    }
}

__global__ __launch_bounds__(256) void coattn_kernel(
    const float* __restrict__ pu, const float* __restrict__ pv,
    const float* __restrict__ a, float* __restrict__ out)
{
    int tid = threadIdx.x;
    int j  = blockIdx.x * 256 + tid;   // lane = j: coalesced pv loads + out stores
    int b  = blockIdx.z;
    int i0 = blockIdx.y * CHUNK;

    float pvr[HH];
    #pragma unroll
    for (int h = 0; h < HH; ++h)
        pvr[h] = pv[((size_t)(b * HH + h)) * ND + j];

    // a[] loads are uniform -> SGPRs.
    float m2a[HH];
    float A = 0.f;
    #pragma unroll
    for (int h = 0; h < HH; ++h) {
        float av = a[h];
        m2a[h] = -2.f * av;
        A += av;
    }

    const float* purow = pu + ((size_t)(b * NC + i0)) * HH;
    float* orow = out + ((size_t)(b * NC + i0)) * ND + j;

    float cur[HH], nxt[HH];
    load_pu_row(cur, purow);           // preload ii = 0

    #pragma unroll
    for (int ii = 0; ii < CHUNK; ++ii) {
        if (ii + 1 < CHUNK)
            load_pu_row(nxt, purow + (ii + 1) * HH);   // prefetch: latency hidden by compute

        float acc0 = A, acc1 = 0.f, acc2 = 0.f, acc3 = 0.f;
        #pragma unroll
        for (int t = 0; t < NPAIR; ++t) {
            if (t < SPLIT) {
                // common-denominator: VALU-heavy, trans-light
                float u   = fmaf(cur[2 * t],     pvr[2 * t],     1.0f);
                float v   = fmaf(cur[2 * t + 1], pvr[2 * t + 1], 1.0f);
                float den = u * v;                          // <= ~1e19, fp32-safe
                float num = fmaf(m2a[2 * t + 1], u, m2a[2 * t] * v);
                float r   = __builtin_amdgcn_rcpf(den);
                if (t & 1) acc1 = fmaf(num, r, acc1);
                else       acc0 = fmaf(num, r, acc0);
            } else {
                // direct: trans-heavy, VALU-light (fills the trans pipe)
                float u  = fmaf(cur[2 * t],     pvr[2 * t],     1.0f);
                float v  = fmaf(cur[2 * t + 1], pvr[2 * t + 1], 1.0f);
                float r0 = __builtin_amdgcn_rcpf(u);
                float r1 = __builtin_amdgcn_rcpf(v);
                acc2 = fmaf(m2a[2 * t],     r0, acc2);
                acc3 = fmaf(m2a[2 * t + 1], r1, acc3);
            }
        }
        orow[ii * ND] = (acc0 + acc1) + (acc2 + acc3);

        #pragma unroll
        for (int h = 0; h < HH; ++h)       // register rename, no real moves
            cur[h] = nxt[h];
    }
}

extern "C" void kernel_launch(void* const* d_in, const int* in_sizes, int n_in,
                              void* d_out, int out_size, void* d_ws, size_t ws_size,
                              hipStream_t stream) {
    const float* cell = (const float*)d_in[0];
    const float* drug = (const float*)d_in[1];
    const float* w_q  = (const float*)d_in[2];
    const float* w_k  = (const float*)d_in[3];
    const float* bias = (const float*)d_in[4];
    const float* a    = (const float*)d_in[5];
    float* out = (float*)d_out;

    float* pu = (float*)d_ws;                      // [B][NC][H]  = 1 MB
    float* pv = pu + (size_t)BB * NC * HH;         // [B][H][ND]  = 1 MB

    proj_cell_kernel<<<dim3(NC / 8, BB), 256, 0, stream>>>(cell, w_k, bias, pu);
    proj_drug_kernel<<<dim3(ND / 64, BB), 256, 0, stream>>>(drug, w_q, pv);
    coattn_kernel<<<dim3(ND / 256, NC / CHUNK, BB), 256, 0, stream>>>(pu, pv, a, out);
}

// Round 6
// 125.605 us; speedup vs baseline: 1.0271x; 1.0271x over previous
//
#include <hip/hip_runtime.h>
#include <hip/hip_bf16.h>

// out[b,i,j] = sum_h a[h] * tanh(ca[b,i,h] + da[b,j,h] + bias[h])
//   tanh(x) = 1 - 2/(e^{2x}+1);  e^{2x} = (pu*2^16)*pv, pu scaled by 2^-16 in prepass.
// 4-way nested common denominator per quad of h:
//   pair:  N01 = a1*u + a0*v, D01 = u*v      (u = pu0*pv0 + 2^-16, etc.)
//   quad:  num = N23*D01 + N01*D23, den = D01*D23, Q = num*rcp(den)
//   out = A + (-2^-15) * sum(Q)   [A = sum a_h; 2 * 2^-16 = 2^-15]
// -> 14 VALU + 1 v_rcp per 4 h (vs 12+2 pairwise): fewer slots, half the rcps.
// Round-5 bug: SCALE literal was 2^-14; fixed to 2^-15 = 3.0517578125e-05.
// Output FLOAT32 (reference dtype).

#define BB    8
#define NC    1024
#define ND    1024
#define DD    64
#define HH    32
#define CHUNK 8
#define C2    2.885390081777927f        // 2*log2(e)
#define EPS16 1.52587890625e-05f        // 2^-16 (exact)
#define SCALE (-3.0517578125e-05f)      // -2^-15 (exact)

__global__ __launch_bounds__(256) void proj_cell_kernel(
    const float* __restrict__ cell, const float* __restrict__ w_k,
    const float* __restrict__ bias, float* __restrict__ pu)
{
    int tid = threadIdx.x;
    int h = tid & 31;
    int i = blockIdx.x * 8 + (tid >> 5);
    int b = blockIdx.y;
    const float* crow = cell + ((size_t)(b * NC + i)) * DD;
    float s = bias[h];
    #pragma unroll
    for (int d = 0; d < DD; ++d)
        s = fmaf(crow[d], w_k[d * HH + h], s);
    // pu' = 2^-16 * e^{2*(ca+bias)}  (scale folded into the exponent, exact)
    pu[((size_t)(b * NC + i)) * HH + h] = exp2f(fmaf(C2, s, -16.0f));
}

// pv layout: [B][H][ND] so the main kernel's pv loads are j-coalesced.
__global__ __launch_bounds__(256) void proj_drug_kernel(
    const float* __restrict__ drug, const float* __restrict__ w_q,
    float* __restrict__ pv)
{
    __shared__ float sd[64][65];   // +1 pad breaks the 32-bank alias
    int tid = threadIdx.x;
    int b = blockIdx.y;
    int j0 = blockIdx.x * 64;
    const float* dbase = drug + ((size_t)(b * ND + j0)) * DD;
    #pragma unroll
    for (int k = 0; k < 16; ++k) {
        int idx = k * 256 + tid;           // coalesced global read
        sd[idx >> 6][idx & 63] = dbase[idx];
    }
    __syncthreads();
    int jl = tid & 63;       // lane = j  -> coalesced pv writes
    int hg = tid >> 6;       // 0..3, wave-uniform h
    #pragma unroll
    for (int hh = 0; hh < 8; ++hh) {
        int h = hg * 8 + hh;
        float s = 0.f;
        #pragma unroll
        for (int d = 0; d < DD; ++d)
            s = fmaf(sd[jl][d], w_q[d * HH + h], s);
        pv[((size_t)(b * HH + h)) * ND + j0 + jl] = exp2f(C2 * s);
    }
}

__global__ __launch_bounds__(256, 6) void coattn_kernel(
    const float* __restrict__ pu, const float* __restrict__ pv,
    const float* __restrict__ a, float* __restrict__ out)
{
    int tid = threadIdx.x;
    int j  = blockIdx.x * 256 + tid;   // lane = j: coalesced pv loads + out stores
    int b  = blockIdx.z;
    int i0 = blockIdx.y * CHUNK;

    float pvr[HH];
    #pragma unroll
    for (int h = 0; h < HH; ++h)
        pvr[h] = pv[((size_t)(b * HH + h)) * ND + j];

    // a[] loads are wave-uniform -> s_load; av stays scalar. No VALU prep.
    float av[HH];
    #pragma unroll
    for (int h = 0; h < HH; ++h)
        av[h] = a[h];
    float A = 0.f;
    #pragma unroll
    for (int h = 0; h < HH; ++h)
        A += av[h];

    const float* purow = pu + ((size_t)(b * NC + i0)) * HH;
    float* orow = out + ((size_t)(b * NC + i0)) * ND + j;

    #pragma unroll
    for (int ii = 0; ii < CHUNK; ++ii) {
        // wave-uniform row of 32 scaled-pu values -> s_load_dwordx4
        float pur[HH];
        #pragma unroll
        for (int h4 = 0; h4 < HH / 4; ++h4) {
            float4 t = reinterpret_cast<const float4*>(purow + ii * HH)[h4];
            pur[4 * h4 + 0] = t.x;
            pur[4 * h4 + 1] = t.y;
            pur[4 * h4 + 2] = t.z;
            pur[4 * h4 + 3] = t.w;
        }

        float acc0 = 0.f, acc1 = 0.f;
        #pragma unroll
        for (int q = 0; q < HH / 4; ++q) {
            float u = fmaf(pur[4 * q + 0], pvr[4 * q + 0], EPS16);  // 2^-16*(1+e^2x)
            float v = fmaf(pur[4 * q + 1], pvr[4 * q + 1], EPS16);
            float w = fmaf(pur[4 * q + 2], pvr[4 * q + 2], EPS16);
            float z = fmaf(pur[4 * q + 3], pvr[4 * q + 3], EPS16);
            float n01 = fmaf(av[4 * q + 1], u, av[4 * q + 0] * v);
            float d01 = u * v;
            float n23 = fmaf(av[4 * q + 3], w, av[4 * q + 2] * z);
            float d23 = w * z;
            float den = d01 * d23;                 // in [2^-64, ~3e8]: fp32-safe
            float num = fmaf(n23, d01, n01 * d23); // <= ~3e6: fp32-safe
            float r   = __builtin_amdgcn_rcpf(den);
            if (q & 1) acc1 = fmaf(num, r, acc1);
            else       acc0 = fmaf(num, r, acc0);
        }
        orow[ii * ND] = fmaf(acc0 + acc1, SCALE, A);   // A - 2^-15 * sum
    }
}

extern "C" void kernel_launch(void* const* d_in, const int* in_sizes, int n_in,
                              void* d_out, int out_size, void* d_ws, size_t ws_size,
                              hipStream_t stream) {
    const float* cell = (const float*)d_in[0];
    const float* drug = (const float*)d_in[1];
    const float* w_q  = (const float*)d_in[2];
    const float* w_k  = (const float*)d_in[3];
    const float* bias = (const float*)d_in[4];
    const float* a    = (const float*)d_in[5];
    float* out = (float*)d_out;

    float* pu = (float*)d_ws;                      // [B][NC][H]  = 1 MB  (scaled 2^-16)
    float* pv = pu + (size_t)BB * NC * HH;         // [B][H][ND]  = 1 MB

    proj_cell_kernel<<<dim3(NC / 8, BB), 256, 0, stream>>>(cell, w_k, bias, pu);
    proj_drug_kernel<<<dim3(ND / 64, BB), 256, 0, stream>>>(drug, w_q, pv);
    coattn_kernel<<<dim3(ND / 256, NC / CHUNK, BB), 256, 0, stream>>>(pu, pv, a, out);
}

// Round 7
// 121.316 us; speedup vs baseline: 1.0634x; 1.0354x over previous
//
#include <hip/hip_runtime.h>
#include <hip/hip_bf16.h>

// out[b,i,j] = sum_h a[h] * tanh(ca[b,i,h] + da[b,j,h] + bias[h])
//   tanh(x) = 1 - 2/(e^{2x}+1);  e^{2x} = (pu*2^16)*pv, pu scaled 2^-16 in prepass.
// Quad common denominator: 14 VALU + 1 v_rcp per 4 h; out = A - 2^-15 * sum(Q).
// coattn v3: pu tile staged in LDS (2 KB/block), read back as wave-uniform
// ds_read_b128 broadcasts -> removes the per-row s_load latency chain that
// left the VALU ~40% idle (rounds 2-6 plateau at ~35us).
// Output FLOAT32 (reference dtype).

#define BB    8
#define NC    1024
#define ND    1024
#define DD    64
#define HH    32
#define CHUNK 16
#define C2    2.885390081777927f        // 2*log2(e)
#define EPS16 1.52587890625e-05f        // 2^-16 (exact)
#define SCALE (-3.0517578125e-05f)      // -2^-15 (exact)

__global__ __launch_bounds__(256) void proj_cell_kernel(
    const float* __restrict__ cell, const float* __restrict__ w_k,
    const float* __restrict__ bias, float* __restrict__ pu)
{
    int tid = threadIdx.x;
    int h = tid & 31;
    int i = blockIdx.x * 8 + (tid >> 5);
    int b = blockIdx.y;
    const float* crow = cell + ((size_t)(b * NC + i)) * DD;
    float s = bias[h];
    #pragma unroll
    for (int d = 0; d < DD; ++d)
        s = fmaf(crow[d], w_k[d * HH + h], s);
    // pu' = 2^-16 * e^{2*(ca+bias)}  (scale folded into the exponent, exact)
    pu[((size_t)(b * NC + i)) * HH + h] = exp2f(fmaf(C2, s, -16.0f));
}

// pv layout: [B][H][ND] so the main kernel's pv loads are j-coalesced.
__global__ __launch_bounds__(256) void proj_drug_kernel(
    const float* __restrict__ drug, const float* __restrict__ w_q,
    float* __restrict__ pv)
{
    __shared__ float sd[64][65];   // +1 pad breaks the 32-bank alias
    int tid = threadIdx.x;
    int b = blockIdx.y;
    int j0 = blockIdx.x * 64;
    const float* dbase = drug + ((size_t)(b * ND + j0)) * DD;
    #pragma unroll
    for (int k = 0; k < 16; ++k) {
        int idx = k * 256 + tid;           // coalesced global read
        sd[idx >> 6][idx & 63] = dbase[idx];
    }
    __syncthreads();
    int jl = tid & 63;       // lane = j  -> coalesced pv writes
    int hg = tid >> 6;       // 0..3, wave-uniform h
    #pragma unroll
    for (int hh = 0; hh < 8; ++hh) {
        int h = hg * 8 + hh;
        float s = 0.f;
        #pragma unroll
        for (int d = 0; d < DD; ++d)
            s = fmaf(sd[jl][d], w_q[d * HH + h], s);
        pv[((size_t)(b * HH + h)) * ND + j0 + jl] = exp2f(C2 * s);
    }
}

__global__ __launch_bounds__(256) void coattn_kernel(
    const float* __restrict__ pu, const float* __restrict__ pv,
    const float* __restrict__ a, float* __restrict__ out)
{
    __shared__ float spu[CHUNK * HH];   // 16 rows x 32 h = 2 KB
    int tid = threadIdx.x;
    int j  = blockIdx.x * 256 + tid;   // lane = j: coalesced pv loads + out stores
    int b  = blockIdx.z;
    int i0 = blockIdx.y * CHUNK;

    // Cooperative pu-tile stage: 512 floats = one float2 per thread, coalesced.
    {
        const float* src = pu + ((size_t)(b * NC + i0)) * HH;
        reinterpret_cast<float2*>(spu)[tid] =
            reinterpret_cast<const float2*>(src)[tid];
    }

    float pvr[HH];
    #pragma unroll
    for (int h = 0; h < HH; ++h)
        pvr[h] = pv[((size_t)(b * HH + h)) * ND + j];

    // a[] loads are wave-uniform -> s_load; stays on the scalar path.
    float av[HH];
    #pragma unroll
    for (int h = 0; h < HH; ++h)
        av[h] = a[h];
    float A = 0.f;
    #pragma unroll
    for (int h = 0; h < HH; ++h)
        A += av[h];

    __syncthreads();

    float* orow = out + ((size_t)(b * NC + i0)) * ND + j;

    #pragma unroll
    for (int ii = 0; ii < CHUNK; ++ii) {
        // wave-uniform LDS broadcast reads: 8x ds_read_b128, no bank conflicts
        float pur[HH];
        #pragma unroll
        for (int h4 = 0; h4 < HH / 4; ++h4) {
            float4 t = reinterpret_cast<const float4*>(spu + ii * HH)[h4];
            pur[4 * h4 + 0] = t.x;
            pur[4 * h4 + 1] = t.y;
            pur[4 * h4 + 2] = t.z;
            pur[4 * h4 + 3] = t.w;
        }

        float acc0 = 0.f, acc1 = 0.f;
        #pragma unroll
        for (int q = 0; q < HH / 4; ++q) {
            float u = fmaf(pur[4 * q + 0], pvr[4 * q + 0], EPS16);  // 2^-16*(1+e^2x)
            float v = fmaf(pur[4 * q + 1], pvr[4 * q + 1], EPS16);
            float w = fmaf(pur[4 * q + 2], pvr[4 * q + 2], EPS16);
            float z = fmaf(pur[4 * q + 3], pvr[4 * q + 3], EPS16);
            float n01 = fmaf(av[4 * q + 1], u, av[4 * q + 0] * v);
            float d01 = u * v;
            float n23 = fmaf(av[4 * q + 3], w, av[4 * q + 2] * z);
            float d23 = w * z;
            float den = d01 * d23;                 // in [2^-64, ~3e8]: fp32-safe
            float num = fmaf(n23, d01, n01 * d23); // <= ~3e6: fp32-safe
            float r   = __builtin_amdgcn_rcpf(den);
            if (q & 1) acc1 = fmaf(num, r, acc1);
            else       acc0 = fmaf(num, r, acc0);
        }
        orow[ii * ND] = fmaf(acc0 + acc1, SCALE, A);   // A - 2^-15 * sum
    }
}

extern "C" void kernel_launch(void* const* d_in, const int* in_sizes, int n_in,
                              void* d_out, int out_size, void* d_ws, size_t ws_size,
                              hipStream_t stream) {
    const float* cell = (const float*)d_in[0];
    const float* drug = (const float*)d_in[1];
    const float* w_q  = (const float*)d_in[2];
    const float* w_k  = (const float*)d_in[3];
    const float* bias = (const float*)d_in[4];
    const float* a    = (const float*)d_in[5];
    float* out = (float*)d_out;

    float* pu = (float*)d_ws;                      // [B][NC][H]  = 1 MB  (scaled 2^-16)
    float* pv = pu + (size_t)BB * NC * HH;         // [B][H][ND]  = 1 MB

    proj_cell_kernel<<<dim3(NC / 8, BB), 256, 0, stream>>>(cell, w_k, bias, pu);
    proj_drug_kernel<<<dim3(ND / 64, BB), 256, 0, stream>>>(drug, w_q, pv);
    coattn_kernel<<<dim3(ND / 256, NC / CHUNK, BB), 256, 0, stream>>>(pu, pv, a, out);
}

// Round 8
// 119.001 us; speedup vs baseline: 1.0841x; 1.0195x over previous
//
#include <hip/hip_runtime.h>
#include <hip/hip_bf16.h>

// out[b,i,j] = sum_h a[h] * tanh(ca[b,i,h] + da[b,j,h] + bias[h])
//   tanh(x) = 1 - 2/(e^{2x}+1);  e^{2x} = (pu*2^16)*pv, pu scaled 2^-16 in prepass.
// Quad common denominator: 14 VALU + 1 v_rcp per 4 h; out = A - 2^-15 * sum(Q).
// coattn v4: 2 consecutive j per thread (float2) -> halves LDS-read/store/loop
// overhead per output and gives 2 independent dep chains per quad (2x ILP).
// pu tile (8 rows x 32 h = 1 KB) staged in LDS, rows read as uniform b128.
// Output FLOAT32 (reference dtype).

#define BB    8
#define NC    1024
#define ND    1024
#define DD    64
#define HH    32
#define CHUNK 8
#define C2    2.885390081777927f        // 2*log2(e)
#define EPS16 1.52587890625e-05f        // 2^-16 (exact)
#define SCALE (-3.0517578125e-05f)      // -2^-15 (exact)

__global__ __launch_bounds__(256) void proj_cell_kernel(
    const float* __restrict__ cell, const float* __restrict__ w_k,
    const float* __restrict__ bias, float* __restrict__ pu)
{
    int tid = threadIdx.x;
    int h = tid & 31;
    int i = blockIdx.x * 8 + (tid >> 5);
    int b = blockIdx.y;
    const float* crow = cell + ((size_t)(b * NC + i)) * DD;
    float s = bias[h];
    #pragma unroll
    for (int d = 0; d < DD; ++d)
        s = fmaf(crow[d], w_k[d * HH + h], s);
    // pu' = 2^-16 * e^{2*(ca+bias)}  (scale folded into the exponent, exact)
    pu[((size_t)(b * NC + i)) * HH + h] = exp2f(fmaf(C2, s, -16.0f));
}

// pv layout: [B][H][ND] so the main kernel's pv loads are j-coalesced.
__global__ __launch_bounds__(256) void proj_drug_kernel(
    const float* __restrict__ drug, const float* __restrict__ w_q,
    float* __restrict__ pv)
{
    __shared__ float sd[64][65];   // +1 pad breaks the 32-bank alias
    int tid = threadIdx.x;
    int b = blockIdx.y;
    int j0 = blockIdx.x * 64;
    const float* dbase = drug + ((size_t)(b * ND + j0)) * DD;
    #pragma unroll
    for (int k = 0; k < 16; ++k) {
        int idx = k * 256 + tid;           // coalesced global read
        sd[idx >> 6][idx & 63] = dbase[idx];
    }
    __syncthreads();
    int jl = tid & 63;       // lane = j  -> coalesced pv writes
    int hg = tid >> 6;       // 0..3, wave-uniform h
    #pragma unroll
    for (int hh = 0; hh < 8; ++hh) {
        int h = hg * 8 + hh;
        float s = 0.f;
        #pragma unroll
        for (int d = 0; d < DD; ++d)
            s = fmaf(sd[jl][d], w_q[d * HH + h], s);
        pv[((size_t)(b * HH + h)) * ND + j0 + jl] = exp2f(C2 * s);
    }
}

__global__ __launch_bounds__(256) void coattn_kernel(
    const float* __restrict__ pu, const float* __restrict__ pv,
    const float* __restrict__ a, float* __restrict__ out)
{
    __shared__ float spu[CHUNK * HH];   // 8 rows x 32 h = 1 KB
    int tid = threadIdx.x;
    int j2  = blockIdx.x * 512 + tid * 2;   // two consecutive j per thread
    int b   = blockIdx.z;
    int i0  = blockIdx.y * CHUNK;

    // Cooperative pu-tile stage: 256 floats = one per thread, coalesced.
    spu[tid] = pu[((size_t)(b * NC + i0)) * HH + tid];

    // Per-thread pv columns: float2 per h, coalesced dwordx2 across the wave.
    float2 pvr[HH];
    #pragma unroll
    for (int h = 0; h < HH; ++h)
        pvr[h] = *reinterpret_cast<const float2*>(&pv[((size_t)(b * HH + h)) * ND + j2]);

    // a[] loads are wave-uniform -> scalar path.
    float av[HH];
    #pragma unroll
    for (int h = 0; h < HH; ++h)
        av[h] = a[h];
    float A = 0.f;
    #pragma unroll
    for (int h = 0; h < HH; ++h)
        A += av[h];

    __syncthreads();

    float* orow = out + ((size_t)(b * NC + i0)) * ND + j2;

    #pragma unroll
    for (int ii = 0; ii < CHUNK; ++ii) {
        // wave-uniform LDS broadcast reads: 8x ds_read_b128, conflict-free
        float pur[HH];
        #pragma unroll
        for (int h4 = 0; h4 < HH / 4; ++h4) {
            float4 t = reinterpret_cast<const float4*>(spu + ii * HH)[h4];
            pur[4 * h4 + 0] = t.x;
            pur[4 * h4 + 1] = t.y;
            pur[4 * h4 + 2] = t.z;
            pur[4 * h4 + 3] = t.w;
        }

        float ax0 = 0.f, ax1 = 0.f, ay0 = 0.f, ay1 = 0.f;
        #pragma unroll
        for (int q = 0; q < HH / 4; ++q) {
            // lane-chain X (j2) and Y (j2+1): fully independent -> 2x ILP
            float ux = fmaf(pur[4 * q + 0], pvr[4 * q + 0].x, EPS16);
            float uy = fmaf(pur[4 * q + 0], pvr[4 * q + 0].y, EPS16);
            float vx = fmaf(pur[4 * q + 1], pvr[4 * q + 1].x, EPS16);
            float vy = fmaf(pur[4 * q + 1], pvr[4 * q + 1].y, EPS16);
            float wx = fmaf(pur[4 * q + 2], pvr[4 * q + 2].x, EPS16);
            float wy = fmaf(pur[4 * q + 2], pvr[4 * q + 2].y, EPS16);
            float zx = fmaf(pur[4 * q + 3], pvr[4 * q + 3].x, EPS16);
            float zy = fmaf(pur[4 * q + 3], pvr[4 * q + 3].y, EPS16);

            float n01x = fmaf(av[4 * q + 1], ux, av[4 * q + 0] * vx);
            float n01y = fmaf(av[4 * q + 1], uy, av[4 * q + 0] * vy);
            float d01x = ux * vx;
            float d01y = uy * vy;
            float n23x = fmaf(av[4 * q + 3], wx, av[4 * q + 2] * zx);
            float n23y = fmaf(av[4 * q + 3], wy, av[4 * q + 2] * zy);
            float d23x = wx * zx;
            float d23y = wy * zy;

            float denx = d01x * d23x;                  // in [2^-64, ~3e8]: fp32-safe
            float deny = d01y * d23y;
            float numx = fmaf(n23x, d01x, n01x * d23x); // <= ~3e6: fp32-safe
            float numy = fmaf(n23y, d01y, n01y * d23y);
            float rx   = __builtin_amdgcn_rcpf(denx);
            float ry   = __builtin_amdgcn_rcpf(deny);
            if (q & 1) { ax1 = fmaf(numx, rx, ax1); ay1 = fmaf(numy, ry, ay1); }
            else       { ax0 = fmaf(numx, rx, ax0); ay0 = fmaf(numy, ry, ay0); }
        }
        float2 res;
        res.x = fmaf(ax0 + ax1, SCALE, A);   // A - 2^-15 * sum
        res.y = fmaf(ay0 + ay1, SCALE, A);
        *reinterpret_cast<float2*>(&orow[(size_t)ii * ND]) = res;
    }
}

extern "C" void kernel_launch(void* const* d_in, const int* in_sizes, int n_in,
                              void* d_out, int out_size, void* d_ws, size_t ws_size,
                              hipStream_t stream) {
    const float* cell = (const float*)d_in[0];
    const float* drug = (const float*)d_in[1];
    const float* w_q  = (const float*)d_in[2];
    const float* w_k  = (const float*)d_in[3];
    const float* bias = (const float*)d_in[4];
    const float* a    = (const float*)d_in[5];
    float* out = (float*)d_out;

    float* pu = (float*)d_ws;                      // [B][NC][H]  = 1 MB  (scaled 2^-16)
    float* pv = pu + (size_t)BB * NC * HH;         // [B][H][ND]  = 1 MB

    proj_cell_kernel<<<dim3(NC / 8, BB), 256, 0, stream>>>(cell, w_k, bias, pu);
    proj_drug_kernel<<<dim3(ND / 64, BB), 256, 0, stream>>>(drug, w_q, pv);
    coattn_kernel<<<dim3(ND / 512, NC / CHUNK, BB), 256, 0, stream>>>(pu, pv, a, out);
}